// Round 2
// baseline (742.838 us; speedup 1.0000x reference)
//
#include <hip/hip_runtime.h>

// out[b, r, c] = (c >= r) ? in[b, triu_index(r, c)] : 0
// triu_index(r,c) = r*M - r*(r-1)/2 + (c - r)   (np.triu_indices row-major order)
//
// Persistent grid-stride kernel. Grid-stride step = 2048 blocks * 256 threads
// = 524,288 quads = exactly TWO (M x M) matrices, so each thread's (row, quad)
// position — and therefore its triangle classification — is loop-invariant.
// The upper/lower/boundary branch hoists out of the loop, leaving three
// specialized streaming loops (zero lanes do store-only, fill-kernel style),
// unrolled for deep memory-level parallelism per wave. Nontemporal stores for
// the write-once output.

constexpr int M = 1024;
constexpr int BATCH = 128;
constexpr int TRIU_LEN = M * (M + 1) / 2;       // 524800
constexpr int QPR = M / 4;                      // 256 quads per row
constexpr int TOTAL_QUADS = BATCH * M * QPR;    // 33,554,432
constexpr int BLOCK = 256;
constexpr int GRID = 2048;
constexpr int NTHREADS = BLOCK * GRID;          // 524,288 = 2 matrices of quads
constexpr int ITERS = TOTAL_QUADS / NTHREADS;   // 64 (batch advances by 2/iter)

static_assert(NTHREADS == 2 * M * QPR, "stride must be exactly 2 matrices");
static_assert(TOTAL_QUADS % NTHREADS == 0, "exact tiling");

// Native clang vector type: __builtin_nontemporal_store requires a pointer to
// scalar-or-vector-of-scalar, which HIP_vector_type (float4) is not.
typedef float v4f __attribute__((ext_vector_type(4)));

__global__ __launch_bounds__(BLOCK) void triu_scatter_kernel(
    const float* __restrict__ in, float* __restrict__ out) {
    const int tid = blockIdx.x * BLOCK + threadIdx.x;   // 0 .. 524287
    const int qc = tid & (QPR - 1);                     // quad within row
    const int r  = (tid >> 8) & (M - 1);                // row (loop-invariant)
    const int b0 = tid >> 18;                           // starting batch: 0 or 1
    const int c0 = qc << 2;

    // input pointer at this row's triu data, offset so p[c] indexes by column
    const int row_base = r * (M - 1) - ((r * (r - 1)) >> 1);
    const float* p = in + b0 * TRIU_LEN + row_base;
    v4f* o = reinterpret_cast<v4f*>(out) + tid;

    if (c0 >= r) {
        // whole quad in upper triangle — pure streaming copy
#pragma unroll 8
        for (int k = 0; k < ITERS; ++k) {
            v4f v;
            v.x = p[c0];
            v.y = p[c0 + 1];
            v.z = p[c0 + 2];
            v.w = p[c0 + 3];
            __builtin_nontemporal_store(v, o);
            p += 2 * TRIU_LEN;
            o += NTHREADS;
        }
    } else if (c0 + 3 < r) {
        // whole quad strictly below diagonal — store-only, fill-kernel shape
        const v4f z = {0.f, 0.f, 0.f, 0.f};
#pragma unroll 8
        for (int k = 0; k < ITERS; ++k) {
            __builtin_nontemporal_store(z, o);
            o += NTHREADS;
        }
    } else {
        // boundary quad: c0 < r <= c0+3 (at most one per row).
        // Clamp addresses (always valid: p[c] defined for c in [r, M-1]) and
        // select, so loads are unconditional and pipeline freely.
        const int c1 = c0 + 1, c2 = c0 + 2, c3 = c0 + 3;
        const bool m1 = (c1 >= r), m2 = (c2 >= r);
        const int a1 = m1 ? c1 : c3;
        const int a2 = m2 ? c2 : c3;
#pragma unroll 4
        for (int k = 0; k < ITERS; ++k) {
            v4f v;
            const float ly = p[a1];
            const float lz = p[a2];
            const float lw = p[c3];                      // c3 >= r always here
            v.x = 0.f;
            v.y = m1 ? ly : 0.f;
            v.z = m2 ? lz : 0.f;
            v.w = lw;
            __builtin_nontemporal_store(v, o);
            p += 2 * TRIU_LEN;
            o += NTHREADS;
        }
    }
}

extern "C" void kernel_launch(void* const* d_in, const int* in_sizes, int n_in,
                              void* d_out, int out_size, void* d_ws, size_t ws_size,
                              hipStream_t stream) {
    const float* in = (const float*)d_in[0];
    float* out = (float*)d_out;
    triu_scatter_kernel<<<GRID, BLOCK, 0, stream>>>(in, out);
}

// Round 3
// 688.126 us; speedup vs baseline: 1.0795x; 1.0795x over previous
//
#include <hip/hip_runtime.h>

// out[b, r, c] = (c >= r) ? in[b, triu_index(r, c)] : 0
// triu_index(r,c) = r*M - r*(r-1)/2 + (c - r)   (np.triu_indices row-major order)
//
// Single-pass in-order sweep (the shape the 6.3 TB/s fill kernel proves out).
// One thread per 8 consecutive output columns (two float4 stores, 32 B
// contiguous per thread): halves wave count vs the 1-quad version and doubles
// per-wave memory-level parallelism, while keeping block-ordered contiguous
// streaming for both loads and stores. Plain cached stores (nontemporal
// regressed in round 1).

constexpr int M = 1024;
constexpr int BATCH = 128;
constexpr int TRIU_LEN = M * (M + 1) / 2;        // 524800
constexpr int PAIRS_PER_ROW = M / 8;             // 128 threads per row
constexpr int BLOCK = 256;
constexpr int TOTAL_PAIRS = BATCH * M * PAIRS_PER_ROW;  // 16,777,216
constexpr int GRID = TOTAL_PAIRS / BLOCK;        // 65536

typedef float v4f __attribute__((ext_vector_type(4)));

__global__ __launch_bounds__(BLOCK) void triu_scatter_kernel(
    const float* __restrict__ in, float* __restrict__ out) {
    const int tid = blockIdx.x * BLOCK + threadIdx.x;   // 0 .. 16,777,215
    const int pc = tid & (PAIRS_PER_ROW - 1);           // 8-col span within row
    const int r  = (tid >> 7) & (M - 1);                // row
    const int b  = tid >> 17;                           // batch
    const int c0 = pc << 3;                             // first column of span

    // p[c] = in[b, triu_index(r, c)], valid for c in [r, M-1]
    const int row_base = r * M - ((r * (r - 1)) >> 1) - r;
    const float* p = in + (long)b * TRIU_LEN + row_base;
    v4f* o = reinterpret_cast<v4f*>(out) + 2 * (size_t)tid;

    v4f v0, v1;
    if (c0 >= r) {
        // whole 8-col span in upper triangle — contiguous coalesced loads
        v0.x = p[c0];     v0.y = p[c0 + 1]; v0.z = p[c0 + 2]; v0.w = p[c0 + 3];
        v1.x = p[c0 + 4]; v1.y = p[c0 + 5]; v1.z = p[c0 + 6]; v1.w = p[c0 + 7];
    } else if (c0 + 7 < r) {
        // whole span strictly below diagonal — store-only
        v0 = (v4f){0.f, 0.f, 0.f, 0.f};
        v1 = (v4f){0.f, 0.f, 0.f, 0.f};
    } else {
        // boundary span: c0 < r <= c0+7 (exactly one per row).
        // Clamp addresses so loads are unconditional (p[r..M-1] always valid),
        // then select — no per-lane divergent loads.
        float t[8];
#pragma unroll
        for (int j = 0; j < 8; ++j) {
            const int c = c0 + j;
            const float lv = p[(c >= r) ? c : r];
            t[j] = (c >= r) ? lv : 0.f;
        }
        v0 = (v4f){t[0], t[1], t[2], t[3]};
        v1 = (v4f){t[4], t[5], t[6], t[7]};
    }

    o[0] = v0;
    o[1] = v1;
}

extern "C" void kernel_launch(void* const* d_in, const int* in_sizes, int n_in,
                              void* d_out, int out_size, void* d_ws, size_t ws_size,
                              hipStream_t stream) {
    const float* in = (const float*)d_in[0];
    float* out = (float*)d_out;
    triu_scatter_kernel<<<GRID, BLOCK, 0, stream>>>(in, out);
}